// Round 5
// baseline (154.997 us; speedup 1.0000x reference)
//
#include <hip/hip_runtime.h>
#include <hip/hip_bf16.h>
#include <stdint.h>

#define HID 1024
#define BLKDIM 128
#define BKT 64              // K-tile depth
#define NKT (HID / BKT)     // 16 K-tiles
#define NBUF 3              // triple buffer: depth-2 prefetch

using short8 = __attribute__((ext_vector_type(8))) short;
using f32x4  = __attribute__((ext_vector_type(4))) float;

__device__ __forceinline__ uint32_t bfround(float f) {
    uint32_t u = __builtin_bit_cast(uint32_t, f);
    return (u + 0x7FFFu + ((u >> 16) & 1u)) >> 16;   // RNE to bf16
}

__device__ __forceinline__ void gld16(const ushort* g, const ushort* lds_base) {
    // async global->LDS: per-lane global src, LDS dest = uniform base + lane*16
    __builtin_amdgcn_global_load_lds(
        (const __attribute__((address_space(1))) void*)g,
        (__attribute__((address_space(3))) void*)lds_base, 16, 0, 0);
}

// ---------------- pre-pass: fp32 -> bf16, 8 elems/thread ----------------
__global__ __launch_bounds__(256)
void cvt_bf16_kernel(const float* __restrict__ src, uint4* __restrict__ dst, int n8) {
    int i = blockIdx.x * blockDim.x + threadIdx.x;
    if (i >= n8) return;
    const float4* s = reinterpret_cast<const float4*>(src) + (size_t)i * 2;
    float4 v0 = s[0], v1 = s[1];
    uint4 w;
    w.x = bfround(v0.x) | (bfround(v0.y) << 16);
    w.y = bfround(v0.z) | (bfround(v0.w) << 16);
    w.z = bfround(v1.x) | (bfround(v1.y) << 16);
    w.w = bfround(v1.z) | (bfround(v1.w) << 16);
    dst[i] = w;
}

// ---------------- main GEMM: 128x256 tile, BK=64, counted-vmcnt pipeline ----------------
// LDS swizzle (T2): 16B slot s within a 128B row is stored at s ^ (row&7).
// Write side: linear global_load_lds dest + pre-swizzled global source k-offset.
// Read side: ds_read column XORed with (row&7). XOR is an involution -> consistent.
__global__ __launch_bounds__(512, 2)
void sdd_pipe_kernel(const ushort* __restrict__ xb, const ushort* __restrict__ wb,
                     const int* __restrict__ rind, const int* __restrict__ cind,
                     float* __restrict__ out) {
    __shared__ ushort sA[NBUF][BLKDIM * BKT];       // 3 x 16 KB
    __shared__ ushort sB[NBUF][2 * BLKDIM * BKT];   // 3 x 32 KB   (total 144 KB)

    int g = blockIdx.x;
    const int nwg = gridDim.x;
    if ((nwg & 7) == 0) {                 // bijective XCD swizzle (nwg % 8 == 0)
        const int cpx = nwg >> 3;
        g = (g & 7) * cpx + (g >> 3);
    }
    const int k0 = g * 2;
    const int r  = rind[k0];

    const int t = threadIdx.x;
    const int w = t >> 6;                 // wave 0..7
    const int l = t & 63;

    // ---- staging role ----
    // swizzled source k-offset (ushorts): slot (l&7) at row-mod-8 (l>>3)
    const int kx = (((l & 7) ^ ((l >> 3) & 7)) * 8);
    // A: wave w stages rows w*16 .. w*16+15 (two 8-row issues)
    const ushort* agb = xb + (size_t)(r * BLKDIM + w * 16 + (l >> 3)) * HID + kx;
    // B: wave w stages panel rows w*32 .. w*32+31 (four 8-row issues), all in one block
    const int cblk = cind[k0 + (w >> 2)];
    const ushort* bgb = wb + (size_t)(cblk * BLKDIM + ((w * 32) & 127) + (l >> 3)) * HID + kx;

    // ---- compute role: 8 waves as 2(M) x 4(N), each 64x64 ----
    const int wr   = (w >> 2) * 64;
    const int wcol = (w & 3) * 64;
    const int lr = l & 15;
    const int s0 = (l >> 4) ^ (l & 7);    // swizzled slot for K-half 0
    const int c0 = s0 * 8;                // ushort column offsets
    const int c1 = (s0 ^ 4) * 8;          // K-half 1

    int aoff[4], boff[4];
#pragma unroll
    for (int m = 0; m < 4; ++m) aoff[m] = (wr + m * 16 + lr) * BKT;
#pragma unroll
    for (int n = 0; n < 4; ++n) boff[n] = (wcol + n * 16 + lr) * BKT;

    f32x4 acc[4][4];
#pragma unroll
    for (int m = 0; m < 4; ++m)
#pragma unroll
        for (int n = 0; n < 4; ++n)
            acc[m][n] = (f32x4){0.f, 0.f, 0.f, 0.f};

    auto stageA = [&](int b, int kt, int i) {
        gld16(agb + (size_t)i * 8 * HID + kt * BKT, &sA[b][w * 1024 + i * 512]);
    };
    auto stageB = [&](int b, int kt, int i) {
        gld16(bgb + (size_t)i * 8 * HID + kt * BKT, &sB[b][w * 2048 + i * 512]);
    };

    // ---- prologue: fill tiles 0 and 1 ----
    stageA(0, 0, 0); stageA(0, 0, 1);
    stageB(0, 0, 0); stageB(0, 0, 1); stageB(0, 0, 2); stageB(0, 0, 3);
    stageA(1, 1, 0); stageA(1, 1, 1);
    stageB(1, 1, 0); stageB(1, 1, 1); stageB(1, 1, 2); stageB(1, 1, 3);
    asm volatile("s_waitcnt vmcnt(6)" ::: "memory");   // tile 0 resident
    __builtin_amdgcn_s_barrier();
    __builtin_amdgcn_sched_barrier(0);

    for (int kt = 0; kt < NKT; ++kt) {
        const int cur = kt % 3;
        const int nxt = (kt + 2) % 3;
        const bool pre = (kt + 2) < NKT;
        const ushort* sa = &sA[cur][0];
        const ushort* sb = &sB[cur][0];

        // ---- phase 0 (K-half 0) ----
        {
            short8 aF[4], bF[4];
#pragma unroll
            for (int m = 0; m < 4; ++m)
                aF[m] = *reinterpret_cast<const short8*>(&sa[aoff[m] + c0]);
#pragma unroll
            for (int n = 0; n < 4; ++n)
                bF[n] = *reinterpret_cast<const short8*>(&sb[boff[n] + c0]);
            if (pre) { stageA(nxt, kt + 2, 0); stageB(nxt, kt + 2, 0); stageB(nxt, kt + 2, 1); }
            __builtin_amdgcn_s_setprio(1);
#pragma unroll
            for (int m = 0; m < 4; ++m)
#pragma unroll
                for (int n = 0; n < 4; ++n)
                    acc[m][n] = __builtin_amdgcn_mfma_f32_16x16x32_bf16(aF[m], bF[n], acc[m][n], 0, 0, 0);
            __builtin_amdgcn_s_setprio(0);
        }
        // ---- phase 1 (K-half 1) ----
        {
            short8 aF[4], bF[4];
#pragma unroll
            for (int m = 0; m < 4; ++m)
                aF[m] = *reinterpret_cast<const short8*>(&sa[aoff[m] + c1]);
#pragma unroll
            for (int n = 0; n < 4; ++n)
                bF[n] = *reinterpret_cast<const short8*>(&sb[boff[n] + c1]);
            if (pre) { stageA(nxt, kt + 2, 1); stageB(nxt, kt + 2, 2); stageB(nxt, kt + 2, 3); }
            __builtin_amdgcn_s_setprio(1);
#pragma unroll
            for (int m = 0; m < 4; ++m)
#pragma unroll
                for (int n = 0; n < 4; ++n)
                    acc[m][n] = __builtin_amdgcn_mfma_f32_16x16x32_bf16(aF[m], bF[n], acc[m][n], 0, 0, 0);
            __builtin_amdgcn_s_setprio(0);
        }
        // ---- tile boundary: counted drain (never 0 in steady state) ----
        if (pre) asm volatile("s_waitcnt vmcnt(6)" ::: "memory");
        else     asm volatile("s_waitcnt vmcnt(0)" ::: "memory");
        __builtin_amdgcn_s_barrier();
        __builtin_amdgcn_sched_barrier(0);
    }

    // ---- epilogue: C/D mapping col=lane&15, row=(lane>>4)*4+j ----
    const int blk = (w & 3) >> 1;
    float* op = out + (size_t)(k0 + blk) * (BLKDIM * BLKDIM);
    const int colbase = (wcol & 64) ? 64 : 0;
    const int rbase = wr + (l >> 4) * 4;
#pragma unroll
    for (int m = 0; m < 4; ++m)
#pragma unroll
        for (int n = 0; n < 4; ++n) {
            const int col = colbase + n * 16 + lr;
#pragma unroll
            for (int j = 0; j < 4; ++j)
                op[(size_t)(rbase + m * 16 + j) * BLKDIM + col] = acc[m][n][j];
        }
}

// ---------------- fallback (validated round-1 kernel) ----------------
__device__ __forceinline__ void store16f(ushort* dst, float4 v0, float4 v1, float4 v2, float4 v3) {
    uint4 w0, w1;
    w0.x = bfround(v0.x) | (bfround(v0.y) << 16);
    w0.y = bfround(v0.z) | (bfround(v0.w) << 16);
    w0.z = bfround(v1.x) | (bfround(v1.y) << 16);
    w0.w = bfround(v1.z) | (bfround(v1.w) << 16);
    w1.x = bfround(v2.x) | (bfround(v2.y) << 16);
    w1.y = bfround(v2.z) | (bfround(v2.w) << 16);
    w1.z = bfround(v3.x) | (bfround(v3.y) << 16);
    w1.w = bfround(v3.z) | (bfround(v3.w) << 16);
    uint4* d = reinterpret_cast<uint4*>(dst);
    d[0] = w0; d[1] = w1;
}

__global__ __launch_bounds__(256, 2)
void sdd_bf16_kernel(const float* __restrict__ x, const float* __restrict__ w1,
                     const int* __restrict__ rind, const int* __restrict__ cind,
                     float* __restrict__ out) {
    __shared__ ushort sA[2][BLKDIM * 32];
    __shared__ ushort sB[2][BLKDIM * 32];
    const int k = blockIdx.x;
    const int t = threadIdx.x;
    const int r = rind[k];
    const int c = cind[k];
    const float* Abase = x  + (size_t)r * BLKDIM * HID;
    const float* Bbase = w1 + (size_t)c * BLKDIM * HID;
    const int srow = t >> 1, shalf = t & 1;
    const float* aptr = Abase + (size_t)srow * HID + shalf * 16;
    const float* bptr = Bbase + (size_t)srow * HID + shalf * 16;
    const int soff = srow * 32 + shalf * 16;
    const int wv = t >> 6, lane = t & 63;
    const int wr = (wv >> 1) * 64, wc = (wv & 1) * 64;
    const int lr = lane & 15, lk = (lane >> 4) * 8;
    f32x4 acc[4][4];
#pragma unroll
    for (int m = 0; m < 4; ++m)
#pragma unroll
        for (int n = 0; n < 4; ++n) acc[m][n] = (f32x4){0.f, 0.f, 0.f, 0.f};
    float4 ra[4], rb[4];
#pragma unroll
    for (int i = 0; i < 4; ++i) {
        ra[i] = *reinterpret_cast<const float4*>(aptr + i * 4);
        rb[i] = *reinterpret_cast<const float4*>(bptr + i * 4);
    }
    store16f(&sA[0][soff], ra[0], ra[1], ra[2], ra[3]);
    store16f(&sB[0][soff], rb[0], rb[1], rb[2], rb[3]);
    __syncthreads();
    for (int kt = 0; kt < 32; ++kt) {
        const int cur = kt & 1;
        if (kt + 1 < 32) {
            const float* ap = aptr + (kt + 1) * 32;
            const float* bp = bptr + (kt + 1) * 32;
#pragma unroll
            for (int i = 0; i < 4; ++i) {
                ra[i] = *reinterpret_cast<const float4*>(ap + i * 4);
                rb[i] = *reinterpret_cast<const float4*>(bp + i * 4);
            }
        }
        const ushort* sa = sA[cur];
        const ushort* sb = sB[cur];
        short8 aF[4], bF[4];
#pragma unroll
        for (int m = 0; m < 4; ++m) aF[m] = *reinterpret_cast<const short8*>(&sa[(wr + m * 16 + lr) * 32 + lk]);
#pragma unroll
        for (int n = 0; n < 4; ++n) bF[n] = *reinterpret_cast<const short8*>(&sb[(wc + n * 16 + lr) * 32 + lk]);
#pragma unroll
        for (int m = 0; m < 4; ++m)
#pragma unroll
            for (int n = 0; n < 4; ++n)
                acc[m][n] = __builtin_amdgcn_mfma_f32_16x16x32_bf16(aF[m], bF[n], acc[m][n], 0, 0, 0);
        if (kt + 1 < 32) {
            store16f(&sA[cur ^ 1][soff], ra[0], ra[1], ra[2], ra[3]);
            store16f(&sB[cur ^ 1][soff], rb[0], rb[1], rb[2], rb[3]);
        }
        __syncthreads();
    }
    float* op = out + (size_t)k * (BLKDIM * BLKDIM);
    const int rbase = wr + (lane >> 4) * 4;
#pragma unroll
    for (int m = 0; m < 4; ++m)
#pragma unroll
        for (int n = 0; n < 4; ++n) {
            const int col = wc + n * 16 + lr;
#pragma unroll
            for (int j = 0; j < 4; ++j)
                op[(size_t)(rbase + m * 16 + j) * BLKDIM + col] = acc[m][n][j];
        }
}

extern "C" void kernel_launch(void* const* d_in, const int* in_sizes, int n_in,
                              void* d_out, int out_size, void* d_ws, size_t ws_size,
                              hipStream_t stream) {
    const float* x  = (const float*)d_in[0];
    const float* w1 = (const float*)d_in[1];
    const int* ri   = (const int*)d_in[2];
    const int* ci   = (const int*)d_in[3];
    float* out      = (float*)d_out;
    const int nnz   = in_sizes[2];
    const int nx    = in_sizes[0];
    const int nw    = in_sizes[1];

    const size_t need = ((size_t)nx + (size_t)nw) * sizeof(ushort);
    if (ws_size >= need && (nnz & 1) == 0) {
        ushort* xb = (ushort*)d_ws;
        ushort* wb = xb + nx;
        const int nx8 = nx / 8, nw8 = nw / 8;
        hipLaunchKernelGGL(cvt_bf16_kernel, dim3((nx8 + 255) / 256), dim3(256), 0, stream,
                           x, (uint4*)xb, nx8);
        hipLaunchKernelGGL(cvt_bf16_kernel, dim3((nw8 + 255) / 256), dim3(256), 0, stream,
                           w1, (uint4*)wb, nw8);
        hipLaunchKernelGGL(sdd_pipe_kernel, dim3(nnz / 2), dim3(512), 0, stream,
                           xb, wb, ri, ci, out);
    } else {
        hipLaunchKernelGGL(sdd_bf16_kernel, dim3(nnz), dim3(256), 0, stream,
                           x, w1, ri, ci, out);
    }
}

// Round 6
// 139.452 us; speedup vs baseline: 1.1115x; 1.1115x over previous
//
#include <hip/hip_runtime.h>
#include <hip/hip_bf16.h>
#include <stdint.h>

#define HID 1024
#define BLKDIM 128
#define BKT 32              // K-tile depth
#define NKT (HID / BKT)     // 32 K-tiles
#define NBUF 3              // triple buffer: depth-2 prefetch

using short8 = __attribute__((ext_vector_type(8))) short;
using f32x4  = __attribute__((ext_vector_type(4))) float;

__device__ __forceinline__ uint32_t bfround(float f) {
    uint32_t u = __builtin_bit_cast(uint32_t, f);
    return (u + 0x7FFFu + ((u >> 16) & 1u)) >> 16;   // RNE to bf16
}

__device__ __forceinline__ void gld16(const ushort* g, const ushort* lds_base) {
    // async global->LDS: per-lane global src, LDS dest = uniform base + lane*16
    __builtin_amdgcn_global_load_lds(
        (const __attribute__((address_space(1))) void*)g,
        (__attribute__((address_space(3))) void*)lds_base, 16, 0, 0);
}

// ---------------- pre-pass: fp32 -> bf16, 8 elems/thread ----------------
__global__ __launch_bounds__(256)
void cvt_bf16_kernel(const float* __restrict__ src, uint4* __restrict__ dst, int n8) {
    int i = blockIdx.x * blockDim.x + threadIdx.x;
    if (i >= n8) return;
    const float4* s = reinterpret_cast<const float4*>(src) + (size_t)i * 2;
    float4 v0 = s[0], v1 = s[1];
    uint4 w;
    w.x = bfround(v0.x) | (bfround(v0.y) << 16);
    w.y = bfround(v0.z) | (bfround(v0.w) << 16);
    w.z = bfround(v1.x) | (bfround(v1.y) << 16);
    w.w = bfround(v1.z) | (bfround(v1.w) << 16);
    dst[i] = w;
}

// ---------------- main GEMM: 128x256 tile, BK=32, counted-vmcnt pipeline, 72 KB LDS ----------------
// LDS layout: row-pairs packed into 128-B super-rows.
//   phys_slot(row, slot4) = (slot4 + 4*(row&1)) ^ ((row>>1)&7)
//   addr_ushort(row, slot4) = (row>>1)*64 + phys_slot*8
// Per 16-lane quarter this gives max 2-way bank aliasing (free).
// Write side: linear global_load_lds dest + inverse-permuted per-lane global source.
__global__ __launch_bounds__(512, 4)
void sdd_pipe2_kernel(const ushort* __restrict__ xb, const ushort* __restrict__ wb,
                      const int* __restrict__ rind, const int* __restrict__ cind,
                      float* __restrict__ out) {
    __shared__ ushort sA[NBUF][BLKDIM * BKT];       // 3 x 8 KB
    __shared__ ushort sB[NBUF][2 * BLKDIM * BKT];   // 3 x 16 KB   (total 72 KB)

    int g = blockIdx.x;
    const int nwg = gridDim.x;
    if ((nwg & 7) == 0) {                 // bijective XCD swizzle
        const int cpx = nwg >> 3;
        g = (g & 7) * cpx + (g >> 3);
    }
    const int k0 = g * 2;
    const int r  = rind[k0];

    const int t = threadIdx.x;
    const int w = t >> 6;                 // wave 0..7
    const int l = t & 63;

    // ---- staging role: lane -> (row_in_16, slot4) via inverse of phys layout ----
    const int unx   = (l & 7) ^ ((l >> 3) & 7);
    const int rin16 = 2 * (l >> 3) + (unx >> 2);
    const int kofs  = (unx & 3) * 8;      // ushort offset within the 32-wide K-tile

    // A: wave w stages rows w*16 .. w*16+15 (1 issue)
    const ushort* agb = xb + (size_t)(r * BLKDIM + w * 16 + rin16) * HID + kofs;
    // B: wave w stages panel rows 32w..32w+31 (2 issues of 16 rows), one column-block
    const int cblk = cind[k0 + (w >> 2)];
    const ushort* bgb = wb + (size_t)(cblk * BLKDIM + (w & 3) * 32 + rin16) * HID + kofs;

    // ---- compute role: 8 waves as 2(M) x 4(N), each 64x64 ----
    const int wr   = (w >> 2) * 64;
    const int wcol = (w & 3) * 64;
    // read addressing: row = base + m*16 + (l&15); slot4 = l>>4
    // (row>>1)&7 = ((l&15)>>1)  [base, m*16 contribute multiples of 8]
    // row&1 = l&1
    const int ps_l = (((l >> 4) + ((l & 1) << 2)) ^ ((l & 15) >> 1)) * 8;  // ushort offset
    const int rhalf = (l & 15) >> 1;      // (row>>1) contribution from lane

    int aoff[4], boff[4];
#pragma unroll
    for (int m = 0; m < 4; ++m) aoff[m] = (wr / 2 + m * 8 + rhalf) * 64 + ps_l;
#pragma unroll
    for (int n = 0; n < 4; ++n) boff[n] = (wcol / 2 + n * 8 + rhalf) * 64 + ps_l;

    f32x4 acc[4][4];
#pragma unroll
    for (int m = 0; m < 4; ++m)
#pragma unroll
        for (int n = 0; n < 4; ++n)
            acc[m][n] = (f32x4){0.f, 0.f, 0.f, 0.f};

    auto stage = [&](int b, int kt) {
        gld16(agb + kt * BKT, &sA[b][w * 512]);
        gld16(bgb + kt * BKT,                      &sB[b][(2 * w) * 512]);
        gld16(bgb + (size_t)16 * HID + kt * BKT,   &sB[b][(2 * w + 1) * 512]);
    };

    // ---- prologue: fill tiles 0 and 1 ----
    stage(0, 0);
    stage(1, 1);
    asm volatile("s_waitcnt vmcnt(3)" ::: "memory");   // tile 0 resident
    __builtin_amdgcn_s_barrier();
    __builtin_amdgcn_sched_barrier(0);

    for (int kt = 0; kt < NKT; ++kt) {
        const int cur = kt % 3;
        const int nxt = (kt + 2) % 3;
        const bool pre = (kt + 2) < NKT;
        const ushort* sa = &sA[cur][0];
        const ushort* sb = &sB[cur][0];

        short8 aF[4], bF[4];
#pragma unroll
        for (int m = 0; m < 4; ++m)
            aF[m] = *reinterpret_cast<const short8*>(&sa[aoff[m]]);
#pragma unroll
        for (int n = 0; n < 4; ++n)
            bF[n] = *reinterpret_cast<const short8*>(&sb[boff[n]]);
        if (pre) stage(nxt, kt + 2);
        __builtin_amdgcn_s_setprio(1);
#pragma unroll
        for (int m = 0; m < 4; ++m)
#pragma unroll
            for (int n = 0; n < 4; ++n)
                acc[m][n] = __builtin_amdgcn_mfma_f32_16x16x32_bf16(aF[m], bF[n], acc[m][n], 0, 0, 0);
        __builtin_amdgcn_s_setprio(0);

        // tile boundary: counted drain (never 0 in steady state)
        if (pre) asm volatile("s_waitcnt vmcnt(3)" ::: "memory");
        else     asm volatile("s_waitcnt vmcnt(0)" ::: "memory");
        __builtin_amdgcn_s_barrier();
        __builtin_amdgcn_sched_barrier(0);
    }

    // ---- epilogue: C/D mapping col=lane&15, row=(lane>>4)*4+j ----
    const int blk = (w & 3) >> 1;
    float* op = out + (size_t)(k0 + blk) * (BLKDIM * BLKDIM);
    const int colbase = (wcol & 64) ? 64 : 0;
    const int lr = l & 15;
    const int rbase = wr + (l >> 4) * 4;
#pragma unroll
    for (int m = 0; m < 4; ++m)
#pragma unroll
        for (int n = 0; n < 4; ++n) {
            const int col = colbase + n * 16 + lr;
#pragma unroll
            for (int j = 0; j < 4; ++j)
                op[(size_t)(rbase + m * 16 + j) * BLKDIM + col] = acc[m][n][j];
        }
}

// ---------------- fallback (validated round-1 kernel) ----------------
__device__ __forceinline__ void store16f(ushort* dst, float4 v0, float4 v1, float4 v2, float4 v3) {
    uint4 w0, w1;
    w0.x = bfround(v0.x) | (bfround(v0.y) << 16);
    w0.y = bfround(v0.z) | (bfround(v0.w) << 16);
    w0.z = bfround(v1.x) | (bfround(v1.y) << 16);
    w0.w = bfround(v1.z) | (bfround(v1.w) << 16);
    w1.x = bfround(v2.x) | (bfround(v2.y) << 16);
    w1.y = bfround(v2.z) | (bfround(v2.w) << 16);
    w1.z = bfround(v3.x) | (bfround(v3.y) << 16);
    w1.w = bfround(v3.z) | (bfround(v3.w) << 16);
    uint4* d = reinterpret_cast<uint4*>(dst);
    d[0] = w0; d[1] = w1;
}

__global__ __launch_bounds__(256, 2)
void sdd_bf16_kernel(const float* __restrict__ x, const float* __restrict__ w1,
                     const int* __restrict__ rind, const int* __restrict__ cind,
                     float* __restrict__ out) {
    __shared__ ushort sA[2][BLKDIM * 32];
    __shared__ ushort sB[2][BLKDIM * 32];
    const int k = blockIdx.x;
    const int t = threadIdx.x;
    const int r = rind[k];
    const int c = cind[k];
    const float* Abase = x  + (size_t)r * BLKDIM * HID;
    const float* Bbase = w1 + (size_t)c * BLKDIM * HID;
    const int srow = t >> 1, shalf = t & 1;
    const float* aptr = Abase + (size_t)srow * HID + shalf * 16;
    const float* bptr = Bbase + (size_t)srow * HID + shalf * 16;
    const int soff = srow * 32 + shalf * 16;
    const int wv = t >> 6, lane = t & 63;
    const int wr = (wv >> 1) * 64, wc = (wv & 1) * 64;
    const int lr = lane & 15, lk = (lane >> 4) * 8;
    f32x4 acc[4][4];
#pragma unroll
    for (int m = 0; m < 4; ++m)
#pragma unroll
        for (int n = 0; n < 4; ++n) acc[m][n] = (f32x4){0.f, 0.f, 0.f, 0.f};
    float4 ra[4], rb[4];
#pragma unroll
    for (int i = 0; i < 4; ++i) {
        ra[i] = *reinterpret_cast<const float4*>(aptr + i * 4);
        rb[i] = *reinterpret_cast<const float4*>(bptr + i * 4);
    }
    store16f(&sA[0][soff], ra[0], ra[1], ra[2], ra[3]);
    store16f(&sB[0][soff], rb[0], rb[1], rb[2], rb[3]);
    __syncthreads();
    for (int kt = 0; kt < 32; ++kt) {
        const int cur = kt & 1;
        if (kt + 1 < 32) {
            const float* ap = aptr + (kt + 1) * 32;
            const float* bp = bptr + (kt + 1) * 32;
#pragma unroll
            for (int i = 0; i < 4; ++i) {
                ra[i] = *reinterpret_cast<const float4*>(ap + i * 4);
                rb[i] = *reinterpret_cast<const float4*>(bp + i * 4);
            }
        }
        const ushort* sa = sA[cur];
        const ushort* sb = sB[cur];
        short8 aF[4], bF[4];
#pragma unroll
        for (int m = 0; m < 4; ++m) aF[m] = *reinterpret_cast<const short8*>(&sa[(wr + m * 16 + lr) * 32 + lk]);
#pragma unroll
        for (int n = 0; n < 4; ++n) bF[n] = *reinterpret_cast<const short8*>(&sb[(wc + n * 16 + lr) * 32 + lk]);
#pragma unroll
        for (int m = 0; m < 4; ++m)
#pragma unroll
            for (int n = 0; n < 4; ++n)
                acc[m][n] = __builtin_amdgcn_mfma_f32_16x16x32_bf16(aF[m], bF[n], acc[m][n], 0, 0, 0);
        if (kt + 1 < 32) {
            store16f(&sA[cur ^ 1][soff], ra[0], ra[1], ra[2], ra[3]);
            store16f(&sB[cur ^ 1][soff], rb[0], rb[1], rb[2], rb[3]);
        }
        __syncthreads();
    }
    float* op = out + (size_t)k * (BLKDIM * BLKDIM);
    const int rbase = wr + (lane >> 4) * 4;
#pragma unroll
    for (int m = 0; m < 4; ++m)
#pragma unroll
        for (int n = 0; n < 4; ++n) {
            const int col = wc + n * 16 + lr;
#pragma unroll
            for (int j = 0; j < 4; ++j)
                op[(size_t)(rbase + m * 16 + j) * BLKDIM + col] = acc[m][n][j];
        }
}

extern "C" void kernel_launch(void* const* d_in, const int* in_sizes, int n_in,
                              void* d_out, int out_size, void* d_ws, size_t ws_size,
                              hipStream_t stream) {
    const float* x  = (const float*)d_in[0];
    const float* w1 = (const float*)d_in[1];
    const int* ri   = (const int*)d_in[2];
    const int* ci   = (const int*)d_in[3];
    float* out      = (float*)d_out;
    const int nnz   = in_sizes[2];
    const int nx    = in_sizes[0];
    const int nw    = in_sizes[1];

    const size_t need = ((size_t)nx + (size_t)nw) * sizeof(ushort);
    if (ws_size >= need && (nnz & 1) == 0) {
        ushort* xb = (ushort*)d_ws;
        ushort* wb = xb + nx;
        const int nx8 = nx / 8, nw8 = nw / 8;
        hipLaunchKernelGGL(cvt_bf16_kernel, dim3((nx8 + 255) / 256), dim3(256), 0, stream,
                           x, (uint4*)xb, nx8);
        hipLaunchKernelGGL(cvt_bf16_kernel, dim3((nw8 + 255) / 256), dim3(256), 0, stream,
                           w1, (uint4*)wb, nw8);
        hipLaunchKernelGGL(sdd_pipe2_kernel, dim3(nnz / 2), dim3(512), 0, stream,
                           xb, wb, ri, ci, out);
    } else {
        hipLaunchKernelGGL(sdd_bf16_kernel, dim3(nnz), dim3(256), 0, stream,
                           x, w1, ri, ci, out);
    }
}